// Round 4
// baseline (1146.922 us; speedup 1.0000x reference)
//
#include <hip/hip_runtime.h>
#include <hip/hip_fp16.h>
#include <stdint.h>

// Problem constants (from reference)
#define NN 100000      // nodes
#define NE 1600000     // edges per set
#define ETOT (NE + NN) // edges + self loops
#define NB 98          // buckets of 1024 nodes (c >> 10)
#define CAP 40         // LDS slots per bucket
#define GRP 8          // flush group (8 x 8B = 64B line)

typedef __attribute__((ext_vector_type(8))) short bf16x8;
typedef __attribute__((ext_vector_type(4))) float f32x4;
typedef __attribute__((ext_vector_type(4))) unsigned short us4;

__device__ __forceinline__ float bf2f(unsigned short u) {
    union { unsigned int i; float f; } x; x.i = ((unsigned int)u) << 16; return x.f;
}
__device__ __forceinline__ unsigned short f2bf(float f) {
    union { float f; unsigned int i; } x; x.f = f;
    unsigned int i = x.i;
    return (unsigned short)((i + 0x7FFFu + ((i >> 16) & 1u)) >> 16);
}

// ---------- CSR build ----------
__global__ void k_init_deg(int* deg0, int* deg1) {
    int i = blockIdx.x * 256 + threadIdx.x;
    if (i < NN) { deg0[i] = 1; deg1[i] = 1; }   // self-loop included
}

// 4 edges/thread, int4 load, 4 independent atomic chains, full grid
__global__ void k_count(const int* col, int* deg) {
    int t = blockIdx.x * 256 + threadIdx.x;
    if (t * 4 >= NE) return;
    int4 a = ((const int4*)col)[t];
    atomicAdd(&deg[a.x], 1); atomicAdd(&deg[a.y], 1);
    atomicAdd(&deg[a.z], 1); atomicAdd(&deg[a.w], 1);
}

// block scans 1024 elems (4/thread); writes inclusive scan into rowptr[i+1]
__global__ void k_scan1(const int* deg, int* rp1, int* bsum) {
    __shared__ int s[256];
    int tid = threadIdx.x;
    int base = blockIdx.x * 1024 + tid * 4;
    int v0 = 0, v1 = 0, v2 = 0, v3 = 0;
    if (base + 0 < NN) v0 = deg[base + 0];
    if (base + 1 < NN) v1 = deg[base + 1];
    if (base + 2 < NN) v2 = deg[base + 2];
    if (base + 3 < NN) v3 = deg[base + 3];
    int sum = v0 + v1 + v2 + v3;
    s[tid] = sum; __syncthreads();
    for (int off = 1; off < 256; off <<= 1) {
        int t = (tid >= off) ? s[tid - off] : 0;
        __syncthreads(); s[tid] += t; __syncthreads();
    }
    int run = s[tid] - sum;
    if (base + 0 < NN) { run += v0; rp1[base + 0] = run; }
    if (base + 1 < NN) { run += v1; rp1[base + 1] = run; }
    if (base + 2 < NN) { run += v2; rp1[base + 2] = run; }
    if (base + 3 < NN) { run += v3; rp1[base + 3] = run; }
    if (tid == 255) bsum[blockIdx.x] = s[255];
}

__global__ void k_scan2(int* bsum, int nb) {  // exclusive scan in-place, nb<=128
    __shared__ int s[128];
    int tid = threadIdx.x;
    int v = (tid < nb) ? bsum[tid] : 0;
    s[tid] = v; __syncthreads();
    for (int off = 1; off < 128; off <<= 1) {
        int t = (tid >= off) ? s[tid - off] : 0;
        __syncthreads(); s[tid] += t; __syncthreads();
    }
    if (tid < nb) bsum[tid] = s[tid] - v;
}

__global__ void k_scan3(int* rowptr, const int* bsum) {
    int tid = threadIdx.x;
    int base = blockIdx.x * 1024 + tid * 4;
    int add = bsum[blockIdx.x];
    #pragma unroll
    for (int i = 0; i < 4; i++) {
        int idx = base + i;
        if (idx < NN) rowptr[idx + 1] += add;
    }
    if (blockIdx.x == 0 && tid == 0) rowptr[0] = 0;
}

// bucket write cursors: partBase[b] = rowptr[b<<10] - (b<<10)  (self-loops excluded)
__global__ void k_initgc(const int* rowptr, int* gcur) {
    int t = threadIdx.x;
    if (t < NB) gcur[t] = rowptr[t << 10] - (t << 10);
}

// Phase 1: multisplit edges into bucket-contiguous part[] with 64B-group flushes.
// record = { payload = row | (b*32767)<<17 , c }
__global__ __launch_bounds__(256) void k_part(const int* er, const int* ec, const float* ew,
                                              int* gcur, uint2* part) {
    __shared__ __align__(64) uint2 buf[NB][CAP];
    __shared__ int cnt[NB];
    int tid = threadIdx.x;
    for (int b = tid; b < NB; b += 256) cnt[b] = 0;
    __syncthreads();
    for (int tile = blockIdx.x; tile < NE / 256; tile += gridDim.x) {
        int idx = tile * 256 + tid;
        int r = er[idx];
        int c = ec[idx];
        float w = ew[idx];
        float bb = fminf(rsqrtf(w), 1.0f);
        unsigned int pay = (unsigned int)r | ((unsigned int)(bb * 32767.f + 0.5f) << 17);
        int b = c >> 10;
        int slot = atomicAdd(&cnt[b], 1);
        if (slot < CAP) {
            buf[b][slot] = make_uint2(pay, (unsigned int)c);
        } else {  // overflow (statistically negligible): direct scattered write
            int pos = atomicAdd(&gcur[b], 1);
            part[pos] = make_uint2(pay, (unsigned int)c);
        }
        __syncthreads();
        for (int b2 = tid; b2 < NB; b2 += 256) {
            int n = min(cnt[b2], CAP);
            int base = 0;
            while (n - base >= GRP) {
                int pos = atomicAdd(&gcur[b2], GRP);
                #pragma unroll
                for (int k = 0; k < GRP; k++) part[pos + k] = buf[b2][base + k];
                base += GRP;
            }
            for (int k = 0; k < n - base; k++) buf[b2][k] = buf[b2][base + k];
            cnt[b2] = n - base;
        }
        __syncthreads();
    }
    // final residual flush (<GRP records per bucket per block)
    for (int b2 = tid; b2 < NB; b2 += 256) {
        int n = min(cnt[b2], CAP);
        if (n > 0) {
            int pos = atomicAdd(&gcur[b2], n);
            for (int k = 0; k < n; k++) part[pos + k] = buf[b2][k];
        }
    }
}

// Phase 2: one block per bucket. Self-loop + cursor + dis init, then L2-local scatter.
__global__ __launch_bounds__(256) void k_scatter(const int* rowptr, const int* deg,
                                                 const uint2* part, unsigned int* eo,
                                                 int* cursor, float* dis) {
    int b = blockIdx.x, tid = threadIdx.x;
    int nlo = b << 10, nhi = min(nlo + 1024, NN);
    for (int i = nlo + tid; i < nhi; i += 256) {
        int p = rowptr[i];
        eo[p] = (unsigned int)i | (32767u << 17);   // self-loop: b=1.0
        cursor[i] = p + 1;
        dis[i] = rsqrtf((float)deg[i]);
    }
    __syncthreads();
    int elo = rowptr[nlo] - nlo;
    int ehi = (b == NB - 1) ? NE : (rowptr[(b + 1) << 10] - ((b + 1) << 10));
    int e = elo + tid;
    for (; e + 768 < ehi; e += 1024) {  // 4-deep ILP
        uint2 r0 = part[e], r1 = part[e + 256], r2 = part[e + 512], r3 = part[e + 768];
        int p0 = atomicAdd(&cursor[r0.y], 1);
        int p1 = atomicAdd(&cursor[r1.y], 1);
        int p2 = atomicAdd(&cursor[r2.y], 1);
        int p3 = atomicAdd(&cursor[r3.y], 1);
        eo[p0] = r0.x; eo[p1] = r1.x; eo[p2] = r2.x; eo[p3] = r3.x;
    }
    for (; e < ehi; e += 256) {
        uint2 r = part[e];
        int p = atomicAdd(&cursor[r.y], 1);
        eo[p] = r.x;
    }
}

// ---------- packing ----------
// Xc[N][256] bf16 = [x | d2an | 0-pad]; 4 cols/thread
__global__ void k_packx(const float* x, const float* d2, unsigned short* Xc) {
    int idx = blockIdx.x * 256 + threadIdx.x;   // NN*64 total
    if (idx >= NN * 64) return;
    int r = idx >> 6, k4 = (idx & 63) << 2;
    us4 o;
    if (k4 < 128) {
        float4 v = *(const float4*)(x + (size_t)r * 128 + k4);
        o[0] = f2bf(v.x); o[1] = f2bf(v.y); o[2] = f2bf(v.z); o[3] = f2bf(v.w);
    } else {
        #pragma unroll
        for (int i = 0; i < 4; i++) {
            int k = k4 + i;
            float v = (k < 226) ? d2[(size_t)r * 98 + (k - 128)] : 0.f;
            o[i] = f2bf(v);
        }
    }
    *(us4*)(Xc + (size_t)r * 256 + k4) = o;
}

// All weights packed in one dispatch, MFMA B-fragment order:
// Wf[ks][ct][lane][j] = Worig[c][k], k = ks*32 + (lane>>4)*8 + j, c = ct*16 + (lane&15)
__global__ void k_packw(const float* wn1, const float* wn2,
                        const float* w1a, const float* w1b,
                        const float* w2a, const float* w2b,
                        const float* w3a, const float* w3b,
                        const float* w4a, const float* w4b,
                        unsigned short* Wfnode, unsigned short* WfL) {
    int idx = blockIdx.x * 256 + threadIdx.x;   // 65536 + 4*32768 = 196608
    if (idx < 65536) {
        int j = idx & 7, lane = (idx >> 3) & 63, ct = (idx >> 9) & 15, ks = idx >> 13;
        int k = ks * 32 + (lane >> 4) * 8 + j;
        int c = ct * 16 + (lane & 15);
        float v = 0.f;
        if (k < 226) v = (c < 128) ? wn1[c * 226 + k] : wn2[(c - 128) * 226 + k];
        Wfnode[idx] = f2bf(v);
    } else if (idx < 196608) {
        int li = idx - 65536;
        int set = li >> 15, r = li & 32767;
        const float* wa = (set == 0) ? w1a : (set == 1) ? w2a : (set == 2) ? w3a : w4a;
        const float* wb = (set == 0) ? w1b : (set == 1) ? w2b : (set == 2) ? w3b : w4b;
        int j = r & 7, lane = (r >> 3) & 63, ct = (r >> 9) & 7, ks = r >> 12;
        int k = ks * 32 + (lane >> 4) * 8 + j;
        int c = ct * 16 + (lane & 15);
        float v = (k < 128) ? wa[c * 128 + k] : wb[c * 128 + (k - 128)];
        WfL[li] = f2bf(v);
    }
}

// ---------- aggregation: one wave per node, 8-deep ILP ----------
// g1 = sum a_e*S[row_e], g2 = sum b_e*S[row_e]; a_e = dis[r]*dis[c], b from payload
template <int SRST, int SOFF>
__global__ __launch_bounds__(256) void k_agg(const unsigned short* S,
                                             const int* rowptr, const unsigned int* eo,
                                             const float* dis, unsigned short* G) {
    int c = blockIdx.x * 4 + (threadIdx.x >> 6);
    int lane = threadIdx.x & 63;
    if (c >= NN) return;
    float disc = dis[c];
    float a0 = 0.f, a1 = 0.f, b0 = 0.f, b1 = 0.f;
    int jb = rowptr[c], je = rowptr[c + 1];
    const unsigned short* Sb = S + SOFF + lane * 2;
    int j = jb;
    for (; j + 8 <= je; j += 8) {
        unsigned int w[8]; float dr[8]; unsigned int u[8];
        #pragma unroll
        for (int i = 0; i < 8; i++) w[i] = eo[j + i];
        #pragma unroll
        for (int i = 0; i < 8; i++) dr[i] = dis[w[i] & 0x1FFFF];
        #pragma unroll
        for (int i = 0; i < 8; i++)
            u[i] = *(const unsigned int*)(Sb + (size_t)(w[i] & 0x1FFFF) * SRST);
        #pragma unroll
        for (int i = 0; i < 8; i++) {
            float a = dr[i] * disc;
            float b = (float)(w[i] >> 17) * (1.0f / 32767.0f);
            float x0 = bf2f((unsigned short)(u[i] & 0xFFFF));
            float x1 = bf2f((unsigned short)(u[i] >> 16));
            a0 += a * x0; a1 += a * x1; b0 += b * x0; b1 += b * x1;
        }
    }
    for (; j + 4 <= je; j += 4) {
        unsigned int w[4]; float dr[4]; unsigned int u[4];
        #pragma unroll
        for (int i = 0; i < 4; i++) w[i] = eo[j + i];
        #pragma unroll
        for (int i = 0; i < 4; i++) dr[i] = dis[w[i] & 0x1FFFF];
        #pragma unroll
        for (int i = 0; i < 4; i++)
            u[i] = *(const unsigned int*)(Sb + (size_t)(w[i] & 0x1FFFF) * SRST);
        #pragma unroll
        for (int i = 0; i < 4; i++) {
            float a = dr[i] * disc;
            float b = (float)(w[i] >> 17) * (1.0f / 32767.0f);
            float x0 = bf2f((unsigned short)(u[i] & 0xFFFF));
            float x1 = bf2f((unsigned short)(u[i] >> 16));
            a0 += a * x0; a1 += a * x1; b0 += b * x0; b1 += b * x1;
        }
    }
    for (; j < je; j++) {
        unsigned int w = eo[j];
        int r = w & 0x1FFFF;
        float a = dis[r] * disc;
        float b = (float)(w >> 17) * (1.0f / 32767.0f);
        unsigned int u = *(const unsigned int*)(Sb + (size_t)r * SRST);
        float x0 = bf2f((unsigned short)(u & 0xFFFF));
        float x1 = bf2f((unsigned short)(u >> 16));
        a0 += a * x0; a1 += a * x1; b0 += b * x0; b1 += b * x1;
    }
    unsigned int* gd = (unsigned int*)(G + (size_t)c * 256);
    gd[lane]      = (unsigned int)f2bf(a0) | ((unsigned int)f2bf(a1) << 16);
    gd[64 + lane] = (unsigned int)f2bf(b0) | ((unsigned int)f2bf(b1) << 16);
}

// ---------- GEMM: C[64 x 128-per-blockIdx.y] = A[N][256] @ Wf, no LDS ----------
// MODE 0: store bf16 plain; 1: store bf16 0.5*relu(T)+0.5*relu(acc); 2: same but f32 to out
template <int MODE>
__global__ __launch_bounds__(256) void k_gemm(const unsigned short* A, int arst,
                                              const unsigned short* Wf, int nct_total,
                                              unsigned short* outB, float* outF,
                                              const unsigned short* T, int orst) {
    int wave = threadIdx.x >> 6, lane = threadIdx.x & 63;
    int m = lane & 15, quad = lane >> 4;
    int row0 = blockIdx.x * 64 + wave * 16;
    int arow = row0 + m;
    bool rowok = arow < NN;
    const unsigned short* Ap = A + (size_t)arow * arst + quad * 8;
    int ctbase = blockIdx.y * 8;
    f32x4 acc[8];
    #pragma unroll
    for (int t = 0; t < 8; t++) acc[t] = (f32x4){0.f, 0.f, 0.f, 0.f};

    #pragma unroll
    for (int ks = 0; ks < 8; ks++) {
        bf16x8 a;
        if (rowok) a = *(const bf16x8*)(Ap + ks * 32);
        else       a = (bf16x8){0, 0, 0, 0, 0, 0, 0, 0};
        const unsigned short* wp = Wf + ((size_t)(ks * nct_total + ctbase) * 64 + lane) * 8;
        #pragma unroll
        for (int t = 0; t < 8; t++) {
            bf16x8 b = *(const bf16x8*)(wp + t * 512);
            acc[t] = __builtin_amdgcn_mfma_f32_16x16x32_bf16(a, b, acc[t], 0, 0, 0);
        }
    }

    int col0 = blockIdx.y * 128;
    #pragma unroll
    for (int t = 0; t < 8; t++) {
        int c = col0 + t * 16 + m;
        #pragma unroll
        for (int rg = 0; rg < 4; rg++) {
            int r = row0 + quad * 4 + rg;
            if (r < NN) {
                float v = acc[t][rg];
                if (MODE == 0) {
                    outB[(size_t)r * orst + c] = f2bf(v);
                } else {
                    float tv = bf2f(T[(size_t)r * 128 + c]);
                    float o = 0.5f * fmaxf(tv, 0.f) + 0.5f * fmaxf(v, 0.f);
                    if (MODE == 1) outB[(size_t)r * orst + c] = f2bf(o);
                    else           outF[(size_t)r * 128 + c] = o;
                }
            }
        }
    }
}

extern "C" void kernel_launch(void* const* d_in, const int* in_sizes, int n_in,
                              void* d_out, int out_size, void* d_ws, size_t ws_size,
                              hipStream_t stream) {
    const float* x      = (const float*)d_in[0];
    const float* d2an   = (const float*)d_in[1];
    const int*   ei0    = (const int*)d_in[2];
    const float* ew0    = (const float*)d_in[3];
    const int*   ei1    = (const int*)d_in[4];
    const float* ew1    = (const float*)d_in[5];
    const float* nodeW1 = (const float*)d_in[6];
    const float* nodeW2 = (const float*)d_in[7];
    const float* W1a = (const float*)d_in[8],  *W1b = (const float*)d_in[9];
    const float* W2a = (const float*)d_in[10], *W2b = (const float*)d_in[11];
    const float* W3a = (const float*)d_in[12], *W3b = (const float*)d_in[13];
    const float* W4a = (const float*)d_in[14], *W4b = (const float*)d_in[15];
    float* out = (float*)d_out;

    // ws carve-out
    char* p = (char*)d_ws;
    auto alloc = [&](size_t bytes) -> char* {
        char* r = p; p += (bytes + 255) & ~(size_t)255; return r;
    };
    unsigned short* bufA   = (unsigned short*)alloc((size_t)NN * 256 * 2); // Xc -> G
    unsigned short* bufB   = (unsigned short*)alloc((size_t)NN * 256 * 2); // P  -> XM
    unsigned short* Tbuf   = (unsigned short*)alloc((size_t)NN * 128 * 2);
    unsigned short* Wfnode = (unsigned short*)alloc(65536 * 2);
    unsigned short* WfL    = (unsigned short*)alloc((size_t)4 * 32768 * 2);
    int*    deg0    = (int*)alloc((size_t)NN * 4);
    int*    deg1    = (int*)alloc((size_t)NN * 4);
    int*    rowptr0 = (int*)alloc((size_t)(NN + 1) * 4);
    int*    rowptr1 = (int*)alloc((size_t)(NN + 1) * 4);
    int*    cursor  = (int*)alloc((size_t)NN * 4);
    int*    bsum    = (int*)alloc(512);
    int*    gcur    = (int*)alloc(NB * 4);
    float*  dis0    = (float*)alloc((size_t)NN * 4);
    float*  dis1    = (float*)alloc((size_t)NN * 4);
    unsigned int* eo0 = (unsigned int*)alloc((size_t)ETOT * 4);
    unsigned int* eo1 = (unsigned int*)alloc((size_t)ETOT * 4);
    uint2*  part    = (uint2*)alloc((size_t)NE * 8);   // reused for both sets

    int nbN  = (NN + 255) / 256;
    int nbE4 = (NE / 4 + 255) / 256;      // 4 edges/thread
    int nbS  = (NN + 1023) / 1024;        // 98 scan blocks
    dim3 gP((NN + 63) / 64, 2);           // P gemm: 256 output cols
    dim3 gL((NN + 63) / 64, 1);           // layer gemms: 128 output cols
    int nbA = (NN + 3) / 4;               // agg: 4 waves/block, 1 wave/node

    // --- degrees + rowptr (both sets) ---
    k_init_deg<<<nbN, 256, 0, stream>>>(deg0, deg1);
    k_count<<<nbE4, 256, 0, stream>>>(ei0 + NE, deg0);
    k_count<<<nbE4, 256, 0, stream>>>(ei1 + NE, deg1);
    k_scan1<<<nbS, 256, 0, stream>>>(deg0, rowptr0 + 1, bsum);
    k_scan2<<<1, 128, 0, stream>>>(bsum, nbS);
    k_scan3<<<nbS, 256, 0, stream>>>(rowptr0, bsum);
    k_scan1<<<nbS, 256, 0, stream>>>(deg1, rowptr1 + 1, bsum);
    k_scan2<<<1, 128, 0, stream>>>(bsum, nbS);
    k_scan3<<<nbS, 256, 0, stream>>>(rowptr1, bsum);

    // --- bucketed CSR build, set0 then set1 (part buffer reused) ---
    k_initgc<<<1, 128, 0, stream>>>(rowptr0, gcur);
    k_part<<<256, 256, 0, stream>>>(ei0, ei0 + NE, ew0, gcur, part);
    k_scatter<<<NB, 256, 0, stream>>>(rowptr0, deg0, part, eo0, cursor, dis0);
    k_initgc<<<1, 128, 0, stream>>>(rowptr1, gcur);
    k_part<<<256, 256, 0, stream>>>(ei1, ei1 + NE, ew1, gcur, part);
    k_scatter<<<NB, 256, 0, stream>>>(rowptr1, deg1, part, eo1, cursor, dis1);

    // --- packing ---
    k_packx<<<(NN * 64 + 255) / 256, 256, 0, stream>>>(x, d2an, bufA);
    k_packw<<<768, 256, 0, stream>>>(nodeW1, nodeW2, W1a, W1b, W2a, W2b,
                                     W3a, W3b, W4a, W4b, Wfnode, WfL);

    // --- round 1: P = [x|d2an] @ [nodeW1|nodeW2]^T  (bufA=Xc -> bufB=P) ---
    k_gemm<0><<<gP, 256, 0, stream>>>(bufA, 256, Wfnode, 16, bufB, nullptr, nullptr, 256);
    // layer0 (set0 on x0p): agg -> G(bufA); T = g1@W1a^T+g2@W1b^T
    k_agg<256, 0><<<nbA, 256, 0, stream>>>(bufB, rowptr0, eo0, dis0, bufA);
    k_gemm<0><<<gL, 256, 0, stream>>>(bufA, 256, WfL, 8, Tbuf, nullptr, nullptr, 128);
    // layer1 (set1 on x1p): agg -> G(bufA); XM = 0.5relu(T)+0.5relu(g@W2) -> bufB
    k_agg<256, 128><<<nbA, 256, 0, stream>>>(bufB, rowptr1, eo1, dis1, bufA);
    k_gemm<1><<<gL, 256, 0, stream>>>(bufA, 256, WfL + 32768, 8, bufB, nullptr, Tbuf, 128);

    // --- round 2 on XM (bufB, stride 128) ---
    k_agg<128, 0><<<nbA, 256, 0, stream>>>(bufB, rowptr0, eo0, dis0, bufA);
    k_gemm<0><<<gL, 256, 0, stream>>>(bufA, 256, WfL + 2 * 32768, 8, Tbuf, nullptr, nullptr, 128);
    k_agg<128, 0><<<nbA, 256, 0, stream>>>(bufB, rowptr1, eo1, dis1, bufA);
    k_gemm<2><<<gL, 256, 0, stream>>>(bufA, 256, WfL + 3 * 32768, 8, nullptr, out, Tbuf, 128);
}

// Round 5
// 959.222 us; speedup vs baseline: 1.1957x; 1.1957x over previous
//
#include <hip/hip_runtime.h>
#include <hip/hip_fp16.h>
#include <stdint.h>

// Problem constants (from reference)
#define NN 100000      // nodes
#define NE 1600000     // edges per set
#define ETOT (NE + NN) // edges + self loops

typedef __attribute__((ext_vector_type(8))) short bf16x8;
typedef __attribute__((ext_vector_type(4))) float f32x4;
typedef __attribute__((ext_vector_type(4))) unsigned short us4;

__device__ __forceinline__ float bf2f(unsigned short u) {
    union { unsigned int i; float f; } x; x.i = ((unsigned int)u) << 16; return x.f;
}
__device__ __forceinline__ unsigned short f2bf(float f) {
    union { float f; unsigned int i; } x; x.f = f;
    unsigned int i = x.i;
    return (unsigned short)((i + 0x7FFFu + ((i >> 16) & 1u)) >> 16);
}
// pack two fp16 coefficients into one int
__device__ __forceinline__ int packab(float a, float b) {
    unsigned int ua = __half_as_ushort(__float2half_rn(a));
    unsigned int ub = __half_as_ushort(__float2half_rn(b));
    return (int)(ua | (ub << 16));
}
__device__ __forceinline__ float2 unpackab(int p) {
    float a = __half2float(__ushort_as_half((unsigned short)(p & 0xFFFF)));
    float b = __half2float(__ushort_as_half((unsigned short)(((unsigned int)p) >> 16)));
    return make_float2(a, b);
}

// ---------- CSR build (blockIdx.y = edge set for all merged kernels) ----------
__global__ void k_init_deg(int* deg0, int* deg1) {
    int i = blockIdx.x * 256 + threadIdx.x;
    if (i < NN) { deg0[i] = 1; deg1[i] = 1; }   // self-loop included
}

// 4 edges/thread, int4 load, 4 independent atomic chains, both sets in one grid
__global__ void k_count(const int* col0, const int* col1, int* deg0, int* deg1) {
    int t = blockIdx.x * 256 + threadIdx.x;
    if (t * 4 >= NE) return;
    const int* col = blockIdx.y ? col1 : col0;
    int* deg = blockIdx.y ? deg1 : deg0;
    int4 a = ((const int4*)col)[t];
    atomicAdd(&deg[a.x], 1); atomicAdd(&deg[a.y], 1);
    atomicAdd(&deg[a.z], 1); atomicAdd(&deg[a.w], 1);
}

// block scans 1024 elems (4/thread); writes inclusive scan into rowptr[i+1]
__global__ void k_scan1(const int* deg0, const int* deg1, int* rp0, int* rp1s, int* bsum) {
    __shared__ int s[256];
    const int* deg = blockIdx.y ? deg1 : deg0;
    int* rp = (blockIdx.y ? rp1s : rp0) + 1;
    int* bs = bsum + blockIdx.y * 128;
    int tid = threadIdx.x;
    int base = blockIdx.x * 1024 + tid * 4;
    int v0 = 0, v1 = 0, v2 = 0, v3 = 0;
    if (base + 0 < NN) v0 = deg[base + 0];
    if (base + 1 < NN) v1 = deg[base + 1];
    if (base + 2 < NN) v2 = deg[base + 2];
    if (base + 3 < NN) v3 = deg[base + 3];
    int sum = v0 + v1 + v2 + v3;
    s[tid] = sum; __syncthreads();
    for (int off = 1; off < 256; off <<= 1) {
        int t = (tid >= off) ? s[tid - off] : 0;
        __syncthreads(); s[tid] += t; __syncthreads();
    }
    int run = s[tid] - sum;
    if (base + 0 < NN) { run += v0; rp[base + 0] = run; }
    if (base + 1 < NN) { run += v1; rp[base + 1] = run; }
    if (base + 2 < NN) { run += v2; rp[base + 2] = run; }
    if (base + 3 < NN) { run += v3; rp[base + 3] = run; }
    if (tid == 255) bs[blockIdx.x] = s[255];
}

__global__ void k_scan2(int* bsum, int nb) {  // per-block exclusive scan, 2 sets
    __shared__ int s[128];
    int* bs = bsum + blockIdx.x * 128;
    int tid = threadIdx.x;
    int v = (tid < nb) ? bs[tid] : 0;
    s[tid] = v; __syncthreads();
    for (int off = 1; off < 128; off <<= 1) {
        int t = (tid >= off) ? s[tid - off] : 0;
        __syncthreads(); s[tid] += t; __syncthreads();
    }
    if (tid < nb) bs[tid] = s[tid] - v;
}

__global__ void k_scan3(int* rp0, int* rp1s, const int* bsum) {
    int* rowptr = blockIdx.y ? rp1s : rp0;
    int add = bsum[blockIdx.y * 128 + blockIdx.x];
    int tid = threadIdx.x;
    int base = blockIdx.x * 1024 + tid * 4;
    #pragma unroll
    for (int i = 0; i < 4; i++) {
        int idx = base + i;
        if (idx < NN) rowptr[idx + 1] += add;
    }
    if (blockIdx.x == 0 && tid == 0) rowptr[0] = 0;
}

// self-loop in slot rowptr[c] (a = 1/deg = dis^2, b = 1); init cursor + dis
__global__ void k_self(const int* rp0, const int* rp1s, const int* deg0, const int* deg1,
                       int2* eo0, int2* eo1, int* cur0, int* cur1, float* dis0, float* dis1) {
    int i = blockIdx.x * 256 + threadIdx.x;
    if (i >= NN) return;
    const int* rowptr = blockIdx.y ? rp1s : rp0;
    const int* deg = blockIdx.y ? deg1 : deg0;
    int2* eo = blockIdx.y ? eo1 : eo0;
    int* cursor = blockIdx.y ? cur1 : cur0;
    float* dis = blockIdx.y ? dis1 : dis0;
    int p = rowptr[i];
    float d = (float)deg[i];
    eo[p] = make_int2(i, packab(1.0f / d, 1.0f));
    cursor[i] = p + 1;
    dis[i] = rsqrtf(d);
}

// direct scatter, 1 edge/thread (full occupancy — R1-proven), both sets
__global__ void k_fill(const int* ei0, const float* ew0, const int* ei1, const float* ew1,
                       int* cur0, int* cur1, const float* dis0, const float* dis1,
                       int2* eo0, int2* eo1) {
    int e = blockIdx.x * 256 + threadIdx.x;
    if (e >= NE) return;
    const int* er = blockIdx.y ? ei1 : ei0;
    const float* ew = blockIdx.y ? ew1 : ew0;
    int* cursor = blockIdx.y ? cur1 : cur0;
    const float* dis = blockIdx.y ? dis1 : dis0;
    int2* eo = blockIdx.y ? eo1 : eo0;
    int r = er[e], c = er[NE + e];
    float a = dis[r] * dis[c];
    float b = fminf(rsqrtf(ew[e]), 1.0f);
    int p = atomicAdd(&cursor[c], 1);
    eo[p] = make_int2(r, packab(a, b));
}

// ---------- packing ----------
// Xc[N][256] bf16 = [x | d2an | 0-pad]; 4 cols/thread
__global__ void k_packx(const float* x, const float* d2, unsigned short* Xc) {
    int idx = blockIdx.x * 256 + threadIdx.x;   // NN*64 total
    if (idx >= NN * 64) return;
    int r = idx >> 6, k4 = (idx & 63) << 2;
    us4 o;
    if (k4 < 128) {
        float4 v = *(const float4*)(x + (size_t)r * 128 + k4);
        o[0] = f2bf(v.x); o[1] = f2bf(v.y); o[2] = f2bf(v.z); o[3] = f2bf(v.w);
    } else {
        #pragma unroll
        for (int i = 0; i < 4; i++) {
            int k = k4 + i;
            float v = (k < 226) ? d2[(size_t)r * 98 + (k - 128)] : 0.f;
            o[i] = f2bf(v);
        }
    }
    *(us4*)(Xc + (size_t)r * 256 + k4) = o;
}

// All weights packed in one dispatch, MFMA B-fragment order:
// Wf[ks][ct][lane][j] = Worig[c][k], k = ks*32 + (lane>>4)*8 + j, c = ct*16 + (lane&15)
__global__ void k_packw(const float* wn1, const float* wn2,
                        const float* w1a, const float* w1b,
                        const float* w2a, const float* w2b,
                        const float* w3a, const float* w3b,
                        const float* w4a, const float* w4b,
                        unsigned short* Wfnode, unsigned short* WfL) {
    int idx = blockIdx.x * 256 + threadIdx.x;   // 65536 + 4*32768 = 196608
    if (idx < 65536) {
        int j = idx & 7, lane = (idx >> 3) & 63, ct = (idx >> 9) & 15, ks = idx >> 13;
        int k = ks * 32 + (lane >> 4) * 8 + j;
        int c = ct * 16 + (lane & 15);
        float v = 0.f;
        if (k < 226) v = (c < 128) ? wn1[c * 226 + k] : wn2[(c - 128) * 226 + k];
        Wfnode[idx] = f2bf(v);
    } else if (idx < 196608) {
        int li = idx - 65536;
        int set = li >> 15, r = li & 32767;
        const float* wa = (set == 0) ? w1a : (set == 1) ? w2a : (set == 2) ? w3a : w4a;
        const float* wb = (set == 0) ? w1b : (set == 1) ? w2b : (set == 2) ? w3b : w4b;
        int j = r & 7, lane = (r >> 3) & 63, ct = (r >> 9) & 7, ks = r >> 12;
        int k = ks * 32 + (lane >> 4) * 8 + j;
        int c = ct * 16 + (lane & 15);
        float v = (k < 128) ? wa[c * 128 + k] : wb[c * 128 + (k - 128)];
        WfL[li] = f2bf(v);
    }
}

// ---------- aggregation: one wave per node, 16/4/1 ILP tiers ----------
// g1 = sum a_e*S[row_e], g2 = sum b_e*S[row_e]; coefficients in edge record
template <int SRST, int SOFF>
__global__ __launch_bounds__(256) void k_agg(const unsigned short* S,
                                             const int* rowptr, const int2* eg,
                                             unsigned short* G) {
    int c = blockIdx.x * 4 + (threadIdx.x >> 6);
    int lane = threadIdx.x & 63;
    if (c >= NN) return;
    float a0 = 0.f, a1 = 0.f, b0 = 0.f, b1 = 0.f;
    int jb = rowptr[c], je = rowptr[c + 1];
    const unsigned short* Sb = S + SOFF + lane * 2;
    int j = jb;
    for (; j + 16 <= je; j += 16) {
        int2 e[16]; unsigned int u[16];
        #pragma unroll
        for (int i = 0; i < 16; i++) e[i] = eg[j + i];
        #pragma unroll
        for (int i = 0; i < 16; i++)
            u[i] = *(const unsigned int*)(Sb + (size_t)e[i].x * SRST);
        #pragma unroll
        for (int i = 0; i < 16; i++) {
            float2 w = unpackab(e[i].y);
            float x0 = bf2f((unsigned short)(u[i] & 0xFFFF));
            float x1 = bf2f((unsigned short)(u[i] >> 16));
            a0 += w.x * x0; a1 += w.x * x1; b0 += w.y * x0; b1 += w.y * x1;
        }
    }
    for (; j + 4 <= je; j += 4) {
        int2 e[4]; unsigned int u[4];
        #pragma unroll
        for (int i = 0; i < 4; i++) e[i] = eg[j + i];
        #pragma unroll
        for (int i = 0; i < 4; i++)
            u[i] = *(const unsigned int*)(Sb + (size_t)e[i].x * SRST);
        #pragma unroll
        for (int i = 0; i < 4; i++) {
            float2 w = unpackab(e[i].y);
            float x0 = bf2f((unsigned short)(u[i] & 0xFFFF));
            float x1 = bf2f((unsigned short)(u[i] >> 16));
            a0 += w.x * x0; a1 += w.x * x1; b0 += w.y * x0; b1 += w.y * x1;
        }
    }
    for (; j < je; j++) {
        int2 e = eg[j];
        unsigned int u = *(const unsigned int*)(Sb + (size_t)e.x * SRST);
        float2 w = unpackab(e.y);
        float x0 = bf2f((unsigned short)(u & 0xFFFF));
        float x1 = bf2f((unsigned short)(u >> 16));
        a0 += w.x * x0; a1 += w.x * x1; b0 += w.y * x0; b1 += w.y * x1;
    }
    unsigned int* gd = (unsigned int*)(G + (size_t)c * 256);
    gd[lane]      = (unsigned int)f2bf(a0) | ((unsigned int)f2bf(a1) << 16);
    gd[64 + lane] = (unsigned int)f2bf(b0) | ((unsigned int)f2bf(b1) << 16);
}

// ---------- GEMM: C[64 x 128-per-blockIdx.y] = A[N][256] @ Wf, no LDS ----------
// MODE 0: store bf16 plain; 1: store bf16 0.5*relu(T)+0.5*relu(acc); 2: same but f32 to out
template <int MODE>
__global__ __launch_bounds__(256) void k_gemm(const unsigned short* A, int arst,
                                              const unsigned short* Wf, int nct_total,
                                              unsigned short* outB, float* outF,
                                              const unsigned short* T, int orst) {
    int wave = threadIdx.x >> 6, lane = threadIdx.x & 63;
    int m = lane & 15, quad = lane >> 4;
    int row0 = blockIdx.x * 64 + wave * 16;
    int arow = row0 + m;
    bool rowok = arow < NN;
    const unsigned short* Ap = A + (size_t)arow * arst + quad * 8;
    int ctbase = blockIdx.y * 8;
    f32x4 acc[8];
    #pragma unroll
    for (int t = 0; t < 8; t++) acc[t] = (f32x4){0.f, 0.f, 0.f, 0.f};

    #pragma unroll
    for (int ks = 0; ks < 8; ks++) {
        bf16x8 a;
        if (rowok) a = *(const bf16x8*)(Ap + ks * 32);
        else       a = (bf16x8){0, 0, 0, 0, 0, 0, 0, 0};
        const unsigned short* wp = Wf + ((size_t)(ks * nct_total + ctbase) * 64 + lane) * 8;
        #pragma unroll
        for (int t = 0; t < 8; t++) {
            bf16x8 b = *(const bf16x8*)(wp + t * 512);
            acc[t] = __builtin_amdgcn_mfma_f32_16x16x32_bf16(a, b, acc[t], 0, 0, 0);
        }
    }

    int col0 = blockIdx.y * 128;
    #pragma unroll
    for (int t = 0; t < 8; t++) {
        int c = col0 + t * 16 + m;
        #pragma unroll
        for (int rg = 0; rg < 4; rg++) {
            int r = row0 + quad * 4 + rg;
            if (r < NN) {
                float v = acc[t][rg];
                if (MODE == 0) {
                    outB[(size_t)r * orst + c] = f2bf(v);
                } else {
                    float tv = bf2f(T[(size_t)r * 128 + c]);
                    float o = 0.5f * fmaxf(tv, 0.f) + 0.5f * fmaxf(v, 0.f);
                    if (MODE == 1) outB[(size_t)r * orst + c] = f2bf(o);
                    else           outF[(size_t)r * 128 + c] = o;
                }
            }
        }
    }
}

extern "C" void kernel_launch(void* const* d_in, const int* in_sizes, int n_in,
                              void* d_out, int out_size, void* d_ws, size_t ws_size,
                              hipStream_t stream) {
    const float* x      = (const float*)d_in[0];
    const float* d2an   = (const float*)d_in[1];
    const int*   ei0    = (const int*)d_in[2];
    const float* ew0    = (const float*)d_in[3];
    const int*   ei1    = (const int*)d_in[4];
    const float* ew1    = (const float*)d_in[5];
    const float* nodeW1 = (const float*)d_in[6];
    const float* nodeW2 = (const float*)d_in[7];
    const float* W1a = (const float*)d_in[8],  *W1b = (const float*)d_in[9];
    const float* W2a = (const float*)d_in[10], *W2b = (const float*)d_in[11];
    const float* W3a = (const float*)d_in[12], *W3b = (const float*)d_in[13];
    const float* W4a = (const float*)d_in[14], *W4b = (const float*)d_in[15];
    float* out = (float*)d_out;

    // ws carve-out
    char* p = (char*)d_ws;
    auto alloc = [&](size_t bytes) -> char* {
        char* r = p; p += (bytes + 255) & ~(size_t)255; return r;
    };
    unsigned short* bufA   = (unsigned short*)alloc((size_t)NN * 256 * 2); // Xc -> G
    unsigned short* bufB   = (unsigned short*)alloc((size_t)NN * 256 * 2); // P  -> XM
    unsigned short* Tbuf   = (unsigned short*)alloc((size_t)NN * 128 * 2);
    unsigned short* Wfnode = (unsigned short*)alloc(65536 * 2);
    unsigned short* WfL    = (unsigned short*)alloc((size_t)4 * 32768 * 2);
    int*    deg0    = (int*)alloc((size_t)NN * 4);
    int*    deg1    = (int*)alloc((size_t)NN * 4);
    int*    rowptr0 = (int*)alloc((size_t)(NN + 1) * 4);
    int*    rowptr1 = (int*)alloc((size_t)(NN + 1) * 4);
    int*    cur0    = (int*)alloc((size_t)NN * 4);
    int*    cur1    = (int*)alloc((size_t)NN * 4);
    int*    bsum    = (int*)alloc(2 * 128 * 4);
    float*  dis0    = (float*)alloc((size_t)NN * 4);
    float*  dis1    = (float*)alloc((size_t)NN * 4);
    int2*   eo0     = (int2*)alloc((size_t)ETOT * 8);
    int2*   eo1     = (int2*)alloc((size_t)ETOT * 8);

    int nbN  = (NN + 255) / 256;
    int nbE1 = (NE + 255) / 256;          // 1 edge/thread
    int nbE4 = (NE / 4 + 255) / 256;      // 4 edges/thread
    int nbS  = (NN + 1023) / 1024;        // 98 scan blocks
    dim3 gP((NN + 63) / 64, 2);           // P gemm: 256 output cols
    dim3 gL((NN + 63) / 64, 1);           // layer gemms: 128 output cols
    int nbA = (NN + 3) / 4;               // agg: 4 waves/block, 1 wave/node

    // --- CSR build, both sets per dispatch (blockIdx.y = set) ---
    k_init_deg<<<nbN, 256, 0, stream>>>(deg0, deg1);
    k_count<<<dim3(nbE4, 2), 256, 0, stream>>>(ei0 + NE, ei1 + NE, deg0, deg1);
    k_scan1<<<dim3(nbS, 2), 256, 0, stream>>>(deg0, deg1, rowptr0, rowptr1, bsum);
    k_scan2<<<2, 128, 0, stream>>>(bsum, nbS);
    k_scan3<<<dim3(nbS, 2), 256, 0, stream>>>(rowptr0, rowptr1, bsum);
    k_self<<<dim3(nbN, 2), 256, 0, stream>>>(rowptr0, rowptr1, deg0, deg1,
                                             eo0, eo1, cur0, cur1, dis0, dis1);
    k_fill<<<dim3(nbE1, 2), 256, 0, stream>>>(ei0, ew0, ei1, ew1,
                                              cur0, cur1, dis0, dis1, eo0, eo1);

    // --- packing ---
    k_packx<<<(NN * 64 + 255) / 256, 256, 0, stream>>>(x, d2an, bufA);
    k_packw<<<768, 256, 0, stream>>>(nodeW1, nodeW2, W1a, W1b, W2a, W2b,
                                     W3a, W3b, W4a, W4b, Wfnode, WfL);

    // --- round 1: P = [x|d2an] @ [nodeW1|nodeW2]^T  (bufA=Xc -> bufB=P) ---
    k_gemm<0><<<gP, 256, 0, stream>>>(bufA, 256, Wfnode, 16, bufB, nullptr, nullptr, 256);
    // layer0 (set0 on x0p): agg -> G(bufA); T = g1@W1a^T+g2@W1b^T
    k_agg<256, 0><<<nbA, 256, 0, stream>>>(bufB, rowptr0, eo0, bufA);
    k_gemm<0><<<gL, 256, 0, stream>>>(bufA, 256, WfL, 8, Tbuf, nullptr, nullptr, 128);
    // layer1 (set1 on x1p): agg -> G(bufA); XM = 0.5relu(T)+0.5relu(g@W2) -> bufB
    k_agg<256, 128><<<nbA, 256, 0, stream>>>(bufB, rowptr1, eo1, bufA);
    k_gemm<1><<<gL, 256, 0, stream>>>(bufA, 256, WfL + 32768, 8, bufB, nullptr, Tbuf, 128);

    // --- round 2 on XM (bufB, stride 128) ---
    k_agg<128, 0><<<nbA, 256, 0, stream>>>(bufB, rowptr0, eo0, bufA);
    k_gemm<0><<<gL, 256, 0, stream>>>(bufA, 256, WfL + 2 * 32768, 8, Tbuf, nullptr, nullptr, 128);
    k_agg<128, 0><<<nbA, 256, 0, stream>>>(bufB, rowptr1, eo1, bufA);
    k_gemm<2><<<gL, 256, 0, stream>>>(bufA, 256, WfL + 3 * 32768, 8, nullptr, out, Tbuf, 128);
}